// Round 14
// baseline (375.916 us; speedup 1.0000x reference)
//
#include <hip/hip_runtime.h>

#define T_   256
#define F_   32
#define NBB  16     // full 16-wide fragments (r12 lesson: never shrink below 16)
#define TPB  512    // 8 waves: 0-3 L1-role, 4-7 L2-role
#define IMW  104
#define PR1  260    // pre1 row stride (f32), 16B-aligned
#define PR2  132

typedef __attribute__((ext_vector_type(8))) short bf16x8;
typedef __attribute__((ext_vector_type(4))) float f32x4;
typedef __attribute__((ext_vector_type(4))) unsigned short ush4;

#define K1f  (-1.44269504f)   // -log2(e)   : sigmoid gates
#define K2f  (-2.88539008f)   // -2*log2(e) : tanh gate & tanh(c)

__device__ __forceinline__ unsigned short bf16_rne(float x){
    unsigned u = __float_as_uint(x);
    u += 0x7FFF + ((u >> 16) & 1);
    return (unsigned short)(u >> 16);
}
__device__ __forceinline__ void bf16_split(float x, unsigned short& h, unsigned short& l){
    h = bf16_rne(x);
    float xr = __uint_as_float(((unsigned)h) << 16);
    l = bf16_rne(x - xr);
}
__device__ __forceinline__ void make_frags_s(const float* __restrict__ p8, float s,
                                             bf16x8& fh, bf16x8& fl){
    #pragma unroll
    for (int e = 0; e < 8; ++e){
        unsigned short h, l; bf16_split(s * p8[e], h, l);
        fh[e] = (short)h; fl[e] = (short)l;
    }
}
__device__ __forceinline__ float sigm_pre(float p){   // p = -log2e*x
    return __builtin_amdgcn_rcpf(1.f + __builtin_amdgcn_exp2f(p));
}
__device__ __forceinline__ float tanh_pre(float p){   // p = -2log2e*x
    return fmaf(2.f, __builtin_amdgcn_rcpf(1.f + __builtin_amdgcn_exp2f(p)), -1.f);
}

#define MFMA(A,B,C) __builtin_amdgcn_mfma_f32_16x16x32_bf16((A),(B),(C),0,0,0)

// LDS-visibility barrier WITHOUT vmcnt drain (x-loads stay in flight).
__device__ __forceinline__ void step_barrier(){
    asm volatile("s_waitcnt lgkmcnt(0)" ::: "memory");
    __builtin_amdgcn_s_barrier();
}

// one full L1 unit-combine; returns h, updates c
__device__ __forceinline__ float unit_combine(float gi, float gf, float gg, float go, float& c){
    const float i_ = sigm_pre(gi);
    const float f_ = sigm_pre(gf);
    const float g_ = tanh_pre(gg);
    const float o_ = sigm_pre(go);
    c = fmaf(f_, c, i_ * g_);
    return o_ * tanh_pre(K2f * c);
}

// (512,2): the proven register envelope (~128 VGPR, benign spill only).
__global__ __launch_bounds__(TPB, 2) void lstm_mfma(
    const float* __restrict__ x,      // [4096,256,32]
    const float* __restrict__ W_ih1,  // [256,32]
    const float* __restrict__ W_hh1,  // [256,64]
    const float* __restrict__ b_ih1,  // [256]
    const float* __restrict__ b_hh1,  // [256]
    const float* __restrict__ W_ih2,  // [128,64]
    const float* __restrict__ W_hh2,  // [128,32]
    const float* __restrict__ b_ih2,  // [128]
    const float* __restrict__ b_hh2,  // [128]
    const float* __restrict__ W_fc1,  // [16,32]
    const float* __restrict__ b_fc1,  // [16]
    const float* __restrict__ W_fc2,  // [1,16]
    const float* __restrict__ b_fc2,  // [1]
    float* __restrict__ out)          // [4096]
{
    const int tid  = threadIdx.x;
    const int lane = tid & 63;
    const int wid  = tid >> 6;        // 0..7
    const int bb   = lane & 15;       // fragment col = batch (all 16 real)
    const int kg   = (lane >> 4) & 3; // k-group of 8
    const int b0   = blockIdx.x * NBB;

    __shared__ __align__(16) unsigned short i1h[2][NBB][IMW], i1l[2][NBB][IMW];
    __shared__ __align__(16) unsigned short i2h[2][NBB][IMW], i2l[2][NBB][IMW];
    __shared__ __align__(16) float pre1[NBB * PR1];
    __shared__ __align__(16) float pre2[NBB * PR2];
    __shared__ float hfin[NBB][32];
    __shared__ float hd[NBB][16];

    // ===== weight fragments (pre-scaled) =====
    bf16x8 wh[4][3], wl[4][3];
    f32x4  bfr[4];
    if (wid < 4){
        #pragma unroll
        for (int g = 0; g < 4; ++g){
            const float s = (g == 2) ? K2f : K1f;
            const int r = 64*g + 16*wid + bb;
            make_frags_s(&W_ih1[r*32 +      8*kg], s, wh[g][0], wl[g][0]);
            make_frags_s(&W_hh1[r*64 +      8*kg], s, wh[g][1], wl[g][1]);
            make_frags_s(&W_hh1[r*64 + 32 + 8*kg], s, wh[g][2], wl[g][2]);
            #pragma unroll
            for (int q = 0; q < 4; ++q){
                const int row = 64*g + 16*wid + 4*kg + q;
                bfr[g][q] = s * (b_ih1[row] + b_hh1[row]);
            }
        }
    } else {
        const int j = wid - 4;
        const float s = (j == 2) ? K2f : K1f;
        #pragma unroll
        for (int tt = 0; tt < 2; ++tt){
            const int r = 32*j + 16*tt + bb;
            make_frags_s(&W_ih2[r*64 +      8*kg], s, wh[tt][0], wl[tt][0]);
            make_frags_s(&W_ih2[r*64 + 32 + 8*kg], s, wh[tt][1], wl[tt][1]);
            make_frags_s(&W_hh2[r*32 +      8*kg], s, wh[tt][2], wl[tt][2]);
            #pragma unroll
            for (int q = 0; q < 4; ++q){
                const int row = 32*j + 16*tt + 4*kg + q;
                bfr[tt][q] = s * (b_ih2[row] + b_hh2[row]);
            }
        }
    }

    // ===== combine ownership (REBALANCED r13->r14) =====
    // L1 threads (tid<256): batch cb1=tid>>4, L1 units 3*j1..3*j1+2 (j1=tid&15)
    const int cb1 = tid >> 4;
    const int u0  = (tid & 15) * 3;          // 0..45
    float c10 = 0.f, c11 = 0.f, c12 = 0.f;
    // L2 threads (tid>=256): lt=tid-256, batch cb2=lt>>4:
    //   L2 units v0,v0+1 (P1) + L1 unit 48+(lt&15) (P2, after their MFMA)
    const int lt  = tid & 255;
    const int cb2 = lt >> 4;
    const int v0  = (lt & 15) * 2;
    const int u1x = 48 + (lt & 15);
    float c20 = 0.f, c21 = 0.f, c1x = 0.f;

    // x-staging on L2 threads (light P1 side): 2 consecutive floats
    const int xf = (lt & 15) * 2;
    const size_t xbase = (size_t)(b0 + cb2) * (T_*F_) + xf;
    float2 xc = make_float2(0.f, 0.f);

    // ===== init =====
    for (int i = tid; i < 2*NBB*IMW; i += TPB){
        (&i1h[0][0][0])[i] = 0; (&i1l[0][0][0])[i] = 0;
        (&i2h[0][0][0])[i] = 0; (&i2l[0][0][0])[i] = 0;
    }
    __syncthreads();
    if (wid >= 4){
        float2 x0 = *(const float2*)&x[xbase];
        unsigned short hh, hl;
        bf16_split(x0.x, hh, hl); i1h[0][cb2][xf]   = hh; i1l[0][cb2][xf]   = hl;
        bf16_split(x0.y, hh, hl); i1h[0][cb2][xf+1] = hh; i1l[0][cb2][xf+1] = hl;
        xc = *(const float2*)&x[xbase + F_];
    }
    __syncthreads();

    // ===== main loop =====
    // P1: L1-MFMA(t)                 ||  L2-combine(t-2) + x-stage(t+1)
    // P2: L1-combine(t) [units 0-47] ||  L2-MFMA(t-1) + L1-combine(t) [units 48-63]
    for (int t = 0; t <= T_ + 1; ++t){
        // ---------- P1 ----------
        if (wid < 4){
            if (t < T_){
                const int cur = t & 1;
                const unsigned short* ph = &i1h[cur][0][0] + bb*IMW + 8*kg;
                const unsigned short* pl = &i1l[cur][0][0] + bb*IMW + 8*kg;
                bf16x8 vh[3], vl[3];
                #pragma unroll
                for (int kb = 0; kb < 3; ++kb){
                    vh[kb] = *(const bf16x8*)(ph + 32*kb);
                    vl[kb] = *(const bf16x8*)(pl + 32*kb);
                }
                __builtin_amdgcn_s_setprio(1);
                f32x4 a0 = bfr[0], a1 = bfr[1], a2 = bfr[2], a3 = bfr[3];
                #pragma unroll
                for (int kb = 0; kb < 3; ++kb){
                    a0 = MFMA(wh[0][kb], vh[kb], a0);
                    a1 = MFMA(wh[1][kb], vh[kb], a1);
                    a2 = MFMA(wh[2][kb], vh[kb], a2);
                    a3 = MFMA(wh[3][kb], vh[kb], a3);
                }
                #pragma unroll
                for (int kb = 0; kb < 3; ++kb){
                    a0 = MFMA(wl[0][kb], vh[kb], a0);
                    a1 = MFMA(wl[1][kb], vh[kb], a1);
                    a2 = MFMA(wl[2][kb], vh[kb], a2);
                    a3 = MFMA(wl[3][kb], vh[kb], a3);
                }
                #pragma unroll
                for (int kb = 0; kb < 3; ++kb){
                    a0 = MFMA(wh[0][kb], vl[kb], a0);
                    a1 = MFMA(wh[1][kb], vl[kb], a1);
                    a2 = MFMA(wh[2][kb], vl[kb], a2);
                    a3 = MFMA(wh[3][kb], vl[kb], a3);
                }
                __builtin_amdgcn_s_setprio(0);
                *(f32x4*)&pre1[bb*PR1 +       16*wid + 4*kg] = a0;
                *(f32x4*)&pre1[bb*PR1 +  64 + 16*wid + 4*kg] = a1;
                *(f32x4*)&pre1[bb*PR1 + 128 + 16*wid + 4*kg] = a2;
                *(f32x4*)&pre1[bb*PR1 + 192 + 16*wid + 4*kg] = a3;
            }
        } else {
            const int m = t - 2;   // L2-combine step
            if (m >= 0 && m < T_){
                const float* p = &pre2[cb2*PR2];
                const float2 gi = *(const float2*)&p[     v0];
                const float2 gf = *(const float2*)&p[32 + v0];
                const float2 gg = *(const float2*)&p[64 + v0];
                const float2 go = *(const float2*)&p[96 + v0];
                const float h0 = unit_combine(gi.x, gf.x, gg.x, go.x, c20);
                const float h1 = unit_combine(gi.y, gf.y, gg.y, go.y, c21);
                unsigned short h0h, h0l, h1h, h1l;
                bf16_split(h0, h0h, h0l); bf16_split(h1, h1h, h1l);
                const int buf = (t - 1) & 1;   // consumed by L2-MFMA(t-1) in P2
                *(unsigned*)&i2h[buf][cb2][64 + v0] = (unsigned)h0h | ((unsigned)h1h << 16);
                *(unsigned*)&i2l[buf][cb2][64 + v0] = (unsigned)h0l | ((unsigned)h1l << 16);
                if (m == T_ - 1){ hfin[cb2][v0] = h0; hfin[cb2][v0+1] = h1; }
            }
            if (t + 1 < T_ && t < T_){
                // stage x(t+1) into i1[(t&1)^1] (read at P1(t+1)); load x(t+2)
                const int nxt = (t & 1) ^ 1;
                unsigned short hh, hl;
                bf16_split(xc.x, hh, hl);
                unsigned w0h = hh, w0l = hl;
                bf16_split(xc.y, hh, hl);
                *(unsigned*)&i1h[nxt][cb2][xf] = w0h | ((unsigned)hh << 16);
                *(unsigned*)&i1l[nxt][cb2][xf] = w0l | ((unsigned)hl << 16);
                const int tn = (t + 2 < T_) ? t + 2 : T_ - 1;
                xc = *(const float2*)&x[xbase + (size_t)tn * F_];
            }
        }
        step_barrier();

        // ---------- P2 ----------
        if (wid < 4){
            if (t < T_){
                const int nxt = (t & 1) ^ 1;
                const float* p = &pre1[cb1*PR1];
                unsigned short HH[3], HL[3];
                {
                    const float h = unit_combine(p[u0  ], p[64+u0  ], p[128+u0  ], p[192+u0  ], c10);
                    bf16_split(h, HH[0], HL[0]);
                }
                {
                    const float h = unit_combine(p[u0+1], p[64+u0+1], p[128+u0+1], p[192+u0+1], c11);
                    bf16_split(h, HH[1], HL[1]);
                }
                {
                    const float h = unit_combine(p[u0+2], p[64+u0+2], p[128+u0+2], p[192+u0+2], c12);
                    bf16_split(h, HH[2], HL[2]);
                }
                const int cu = t & 1;
                #pragma unroll
                for (int q = 0; q < 3; ++q){
                    i1h[nxt][cb1][32 + u0 + q] = HH[q];
                    i1l[nxt][cb1][32 + u0 + q] = HL[q];
                    i2h[cu][cb1][u0 + q]       = HH[q];
                    i2l[cu][cb1][u0 + q]       = HL[q];
                }
            }
        } else {
            const int k = t - 1;   // L2-MFMA step
            if (k >= 0 && k < T_){
                const int buf = k & 1;
                const unsigned short* ph = &i2h[buf][0][0] + bb*IMW + 8*kg;
                const unsigned short* pl = &i2l[buf][0][0] + bb*IMW + 8*kg;
                bf16x8 vh[3], vl[3];
                #pragma unroll
                for (int kb = 0; kb < 3; ++kb){
                    vh[kb] = *(const bf16x8*)(ph + 32*kb);
                    vl[kb] = *(const bf16x8*)(pl + 32*kb);
                }
                __builtin_amdgcn_s_setprio(1);
                f32x4 a0 = bfr[0], a1 = bfr[1];
                #pragma unroll
                for (int kb = 0; kb < 3; ++kb){
                    a0 = MFMA(wh[0][kb], vh[kb], a0);
                    a1 = MFMA(wh[1][kb], vh[kb], a1);
                }
                #pragma unroll
                for (int kb = 0; kb < 3; ++kb){
                    a0 = MFMA(wl[0][kb], vh[kb], a0);
                    a1 = MFMA(wl[1][kb], vh[kb], a1);
                }
                #pragma unroll
                for (int kb = 0; kb < 3; ++kb){
                    a0 = MFMA(wh[0][kb], vl[kb], a0);
                    a1 = MFMA(wh[1][kb], vl[kb], a1);
                }
                __builtin_amdgcn_s_setprio(0);
                const int j = wid - 4;
                *(f32x4*)&pre2[bb*PR2 + 32*j +      4*kg] = a0;
                *(f32x4*)&pre2[bb*PR2 + 32*j + 16 + 4*kg] = a1;
            }
            if (t < T_){
                // tail L1-combine: unit u1x = 48 + (lt&15), batch cb2
                const int nxt = (t & 1) ^ 1;
                const float* p = &pre1[cb2*PR1];
                const float h = unit_combine(p[u1x], p[64+u1x], p[128+u1x], p[192+u1x], c1x);
                unsigned short hh, hl; bf16_split(h, hh, hl);
                const int cu = t & 1;
                i1h[nxt][cb2][32 + u1x] = hh;
                i1l[nxt][cb2][32 + u1x] = hl;
                i2h[cu][cb2][u1x]       = hh;
                i2l[cu][cb2][u1x]       = hl;
            }
        }
        step_barrier();
    }

    __syncthreads();
    // ===== head: fc1(16)+relu, fc2(1) =====
    if (tid < NBB * 16){
        const int b = tid >> 4, j2 = tid & 15;
        float a = b_fc1[j2];
        #pragma unroll
        for (int k = 0; k < 32; ++k) a = fmaf(W_fc1[j2*32 + k], hfin[b][k], a);
        hd[b][j2] = fmaxf(a, 0.f);
    }
    __syncthreads();
    if (tid < NBB){
        float a = b_fc2[0];
        #pragma unroll
        for (int k = 0; k < 16; ++k) a = fmaf(W_fc2[k], hd[tid][k], a);
        out[b0 + tid] = a;
    }
}

extern "C" void kernel_launch(void* const* d_in, const int* in_sizes, int n_in,
                              void* d_out, int out_size, void* d_ws, size_t ws_size,
                              hipStream_t stream) {
    const float* x     = (const float*)d_in[0];
    const float* W_ih1 = (const float*)d_in[1];
    const float* W_hh1 = (const float*)d_in[2];
    const float* b_ih1 = (const float*)d_in[3];
    const float* b_hh1 = (const float*)d_in[4];
    const float* W_ih2 = (const float*)d_in[5];
    const float* W_hh2 = (const float*)d_in[6];
    const float* b_ih2 = (const float*)d_in[7];
    const float* b_hh2 = (const float*)d_in[8];
    const float* W_fc1 = (const float*)d_in[9];
    const float* b_fc1 = (const float*)d_in[10];
    const float* W_fc2 = (const float*)d_in[11];
    const float* b_fc2 = (const float*)d_in[12];
    float* out = (float*)d_out;

    const int B = in_sizes[0] / (T_ * F_);   // 4096
    dim3 grid(B / NBB), block(TPB);          // 256 blocks, 1/CU
    hipLaunchKernelGGL(lstm_mfma, grid, block, 0, stream,
                       x, W_ih1, W_hh1, b_ih1, b_hh1,
                       W_ih2, W_hh2, b_ih2, b_hh2,
                       W_fc1, b_fc1, W_fc2, b_fc2, out);
}

// Round 15
// 320.856 us; speedup vs baseline: 1.1716x; 1.1716x over previous
//
#include <hip/hip_runtime.h>

#define T_   256
#define F_   32
#define NBB  16     // full 16-wide fragments
#define TPB  512    // 8 waves, all identical role-mix
#define IMW  104
#define PR1  260    // pre1 row stride (f32), 16B-aligned
#define PR2  132

typedef __attribute__((ext_vector_type(8))) short bf16x8;
typedef __attribute__((ext_vector_type(4))) float f32x4;

#define K1f  (-1.44269504f)   // -log2(e)   : sigmoid gates
#define K2f  (-2.88539008f)   // -2*log2(e) : tanh gate & tanh(c)

__device__ __forceinline__ unsigned short bf16_rne(float x){
    unsigned u = __float_as_uint(x);
    u += 0x7FFF + ((u >> 16) & 1);
    return (unsigned short)(u >> 16);
}
__device__ __forceinline__ void bf16_split(float x, unsigned short& h, unsigned short& l){
    h = bf16_rne(x);
    float xr = __uint_as_float(((unsigned)h) << 16);
    l = bf16_rne(x - xr);
}
__device__ __forceinline__ void make_frags_s(const float* __restrict__ p8, float s,
                                             bf16x8& fh, bf16x8& fl){
    #pragma unroll
    for (int e = 0; e < 8; ++e){
        unsigned short h, l; bf16_split(s * p8[e], h, l);
        fh[e] = (short)h; fl[e] = (short)l;
    }
}
__device__ __forceinline__ float sigm_pre(float p){   // p = -log2e*x
    return __builtin_amdgcn_rcpf(1.f + __builtin_amdgcn_exp2f(p));
}
__device__ __forceinline__ float tanh_pre(float p){   // p = -2log2e*x
    return fmaf(2.f, __builtin_amdgcn_rcpf(1.f + __builtin_amdgcn_exp2f(p)), -1.f);
}
__device__ __forceinline__ float unit_combine(float gi, float gf, float gg, float go, float& c){
    const float i_ = sigm_pre(gi);
    const float f_ = sigm_pre(gf);
    const float g_ = tanh_pre(gg);
    const float o_ = sigm_pre(go);
    c = fmaf(f_, c, i_ * g_);
    return o_ * tanh_pre(K2f * c);
}

#define MFMA(A,B,C) __builtin_amdgcn_mfma_f32_16x16x32_bf16((A),(B),(C),0,0,0)

// LDS-visibility barrier WITHOUT vmcnt drain (x-loads stay in flight).
__device__ __forceinline__ void step_barrier(){
    asm volatile("s_waitcnt lgkmcnt(0)" ::: "memory");
    __builtin_amdgcn_s_barrier();
}

// (512,2): proven register envelope. Uniform role-mix needs ~140 VGPR/wave.
__global__ __launch_bounds__(TPB, 2) void lstm_mfma(
    const float* __restrict__ x,      // [4096,256,32]
    const float* __restrict__ W_ih1,  // [256,32]
    const float* __restrict__ W_hh1,  // [256,64]
    const float* __restrict__ b_ih1,  // [256]
    const float* __restrict__ b_hh1,  // [256]
    const float* __restrict__ W_ih2,  // [128,64]
    const float* __restrict__ W_hh2,  // [128,32]
    const float* __restrict__ b_ih2,  // [128]
    const float* __restrict__ b_hh2,  // [128]
    const float* __restrict__ W_fc1,  // [16,32]
    const float* __restrict__ b_fc1,  // [16]
    const float* __restrict__ W_fc2,  // [1,16]
    const float* __restrict__ b_fc2,  // [1]
    float* __restrict__ out)          // [4096]
{
    const int tid  = threadIdx.x;
    const int lane = tid & 63;
    const int wid  = tid >> 6;        // 0..7
    const int bb   = lane & 15;       // fragment col = batch
    const int kg   = (lane >> 4) & 3; // k-group of 8
    const int b0   = blockIdx.x * NBB;

    __shared__ __align__(16) unsigned short i1h[2][NBB][IMW], i1l[2][NBB][IMW];
    __shared__ __align__(16) unsigned short i2h[2][NBB][IMW], i2l[2][NBB][IMW];
    __shared__ __align__(16) float pre1[NBB * PR1];
    __shared__ __align__(16) float pre2[NBB * PR2];
    __shared__ float hfin[NBB][32];
    __shared__ float hd[NBB][16];

    // ===== weight fragments: UNIFORM distribution =====
    // L1: wave owns tiles 2*wid, 2*wid+1 of 16 (tile T: gate T>>2, rowblock T&3)
    // L2: wave owns tile wid of 8 (gate wid>>1, rowblock wid&1)
    bf16x8 w1h[2][3], w1l[2][3], w2h[3], w2l[3];
    f32x4  b1f[2], b2f;
    int off1[2];
    #pragma unroll
    for (int tt = 0; tt < 2; ++tt){
        const int Tt = 2*wid + tt;
        const int g  = Tt >> 2, rb = Tt & 3;
        const float s = (g == 2) ? K2f : K1f;
        off1[tt] = 64*g + 16*rb;
        const int r = off1[tt] + bb;
        make_frags_s(&W_ih1[r*32 +      8*kg], s, w1h[tt][0], w1l[tt][0]);
        make_frags_s(&W_hh1[r*64 +      8*kg], s, w1h[tt][1], w1l[tt][1]);
        make_frags_s(&W_hh1[r*64 + 32 + 8*kg], s, w1h[tt][2], w1l[tt][2]);
        #pragma unroll
        for (int q = 0; q < 4; ++q){
            const int row = off1[tt] + 4*kg + q;
            b1f[tt][q] = s * (b_ih1[row] + b_hh1[row]);
        }
    }
    const int g2   = wid >> 1;
    const int off2 = 32*g2 + 16*(wid & 1);
    {
        const float s = (g2 == 2) ? K2f : K1f;
        const int r = off2 + bb;
        make_frags_s(&W_ih2[r*64 +      8*kg], s, w2h[0], w2l[0]);
        make_frags_s(&W_ih2[r*64 + 32 + 8*kg], s, w2h[1], w2l[1]);
        make_frags_s(&W_hh2[r*32 +      8*kg], s, w2h[2], w2l[2]);
        #pragma unroll
        for (int q = 0; q < 4; ++q){
            const int row = off2 + 4*kg + q;
            b2f[q] = s * (b_ih2[row] + b_hh2[row]);
        }
    }

    // ===== combine/x ownership: thread (cb, uu) =====
    const int cb = tid >> 5;          // batch 0..15
    const int uu = tid & 31;
    const int u0 = uu * 2;            // L1 units u0, u0+1 (even -> dword-aligned)
    float c1a = 0.f, c1b = 0.f, c2 = 0.f;
    const size_t xbase = (size_t)(b0 + cb) * (T_*F_) + uu;
    float xc = 0.f;

    // ===== init: zero images, stage x(0), preload x(1) =====
    for (int i = tid; i < 2*NBB*IMW; i += TPB){
        (&i1h[0][0][0])[i] = 0; (&i1l[0][0][0])[i] = 0;
        (&i2h[0][0][0])[i] = 0; (&i2l[0][0][0])[i] = 0;
    }
    __syncthreads();
    {
        unsigned short hh, hl; bf16_split(x[xbase], hh, hl);
        i1h[0][cb][uu] = hh; i1l[0][cb][uu] = hl;
        xc = x[xbase + F_];
    }
    __syncthreads();

    // ===== main loop: 2 phases/step, uniform work on every wave =====
    // P1(t): L1-MFMA(t)->pre1  |  L2-combine(t-2)->h2->i2[nxt]  |  x(t+1)->i1[nxt]
    // P2(t): L1-combine(t)->h1->i1[nxt],i2[cur]  |  L2-MFMA(t-1) from i2[nxt]->pre2
    for (int t = 0; t <= T_ + 1; ++t){
        const int cur = t & 1, nxt = cur ^ 1;

        // ---------- P1 ----------
        const int m = t - 2;
        float q0, q1, q2, q3;
        if (m >= 0 && m < T_){   // hoist pre2 loads before the MFMA block
            const float* p = &pre2[cb*PR2];
            q0 = p[uu]; q1 = p[32 + uu]; q2 = p[64 + uu]; q3 = p[96 + uu];
        }
        if (t < T_){
            const unsigned short* ph = &i1h[cur][0][0] + bb*IMW + 8*kg;
            const unsigned short* pl = &i1l[cur][0][0] + bb*IMW + 8*kg;
            bf16x8 vh[3], vl[3];
            #pragma unroll
            for (int kb = 0; kb < 3; ++kb){
                vh[kb] = *(const bf16x8*)(ph + 32*kb);
                vl[kb] = *(const bf16x8*)(pl + 32*kb);
            }
            __builtin_amdgcn_s_setprio(1);
            f32x4 a0 = b1f[0], a1 = b1f[1];
            #pragma unroll
            for (int kb = 0; kb < 3; ++kb){
                a0 = MFMA(w1h[0][kb], vh[kb], a0);
                a1 = MFMA(w1h[1][kb], vh[kb], a1);
            }
            #pragma unroll
            for (int kb = 0; kb < 3; ++kb){
                a0 = MFMA(w1l[0][kb], vh[kb], a0);
                a1 = MFMA(w1l[1][kb], vh[kb], a1);
            }
            #pragma unroll
            for (int kb = 0; kb < 3; ++kb){
                a0 = MFMA(w1h[0][kb], vl[kb], a0);
                a1 = MFMA(w1h[1][kb], vl[kb], a1);
            }
            __builtin_amdgcn_s_setprio(0);
            *(f32x4*)&pre1[bb*PR1 + off1[0] + 4*kg] = a0;
            *(f32x4*)&pre1[bb*PR1 + off1[1] + 4*kg] = a1;
        }
        if (m >= 0 && m < T_){
            const float h2 = unit_combine(q0, q1, q2, q3, c2);
            unsigned short hh, hl; bf16_split(h2, hh, hl);
            i2h[nxt][cb][64 + uu] = hh;   // consumed by L2-MFMA(t-1) in P2(t)
            i2l[nxt][cb][64 + uu] = hl;
            if (m == T_ - 1) hfin[cb][uu] = h2;
        }
        if (t + 1 < T_){
            unsigned short hh, hl; bf16_split(xc, hh, hl);
            i1h[nxt][cb][uu] = hh; i1l[nxt][cb][uu] = hl;
            const int tn = (t + 2 < T_) ? t + 2 : T_ - 1;
            xc = x[xbase + (size_t)tn * F_];
        }
        step_barrier();

        // ---------- P2 ----------
        float2 gi, gf, gg, go;
        if (t < T_){   // hoist pre1 loads before the MFMA block
            const float* p = &pre1[cb*PR1];
            gi = *(const float2*)&p[      u0];
            gf = *(const float2*)&p[ 64 + u0];
            gg = *(const float2*)&p[128 + u0];
            go = *(const float2*)&p[192 + u0];
        }
        const int k = t - 1;
        if (k >= 0 && k < T_){
            // L2-MFMA(k): i2[nxt] = [h1(k) | h2(k-1)]
            const unsigned short* ph = &i2h[nxt][0][0] + bb*IMW + 8*kg;
            const unsigned short* pl = &i2l[nxt][0][0] + bb*IMW + 8*kg;
            bf16x8 vh[3], vl[3];
            #pragma unroll
            for (int kb = 0; kb < 3; ++kb){
                vh[kb] = *(const bf16x8*)(ph + 32*kb);
                vl[kb] = *(const bf16x8*)(pl + 32*kb);
            }
            __builtin_amdgcn_s_setprio(1);
            f32x4 a = b2f;
            #pragma unroll
            for (int kb = 0; kb < 3; ++kb) a = MFMA(w2h[kb], vh[kb], a);
            #pragma unroll
            for (int kb = 0; kb < 3; ++kb) a = MFMA(w2l[kb], vh[kb], a);
            #pragma unroll
            for (int kb = 0; kb < 3; ++kb) a = MFMA(w2h[kb], vl[kb], a);
            __builtin_amdgcn_s_setprio(0);
            *(f32x4*)&pre2[bb*PR2 + off2 + 4*kg] = a;
        }
        if (t < T_){
            const float h0 = unit_combine(gi.x, gf.x, gg.x, go.x, c1a);
            const float h1 = unit_combine(gi.y, gf.y, gg.y, go.y, c1b);
            unsigned short h0h, h0l, h1h, h1l;
            bf16_split(h0, h0h, h0l); bf16_split(h1, h1h, h1l);
            const unsigned wh_ = (unsigned)h0h | ((unsigned)h1h << 16);
            const unsigned wl_ = (unsigned)h0l | ((unsigned)h1l << 16);
            *(unsigned*)&i1h[nxt][cb][32 + u0] = wh_;   // h1(t) for L1-MFMA(t+1)
            *(unsigned*)&i1l[nxt][cb][32 + u0] = wl_;
            *(unsigned*)&i2h[cur][cb][u0]      = wh_;   // h1(t) for L2-MFMA(t)
            *(unsigned*)&i2l[cur][cb][u0]      = wl_;
        }
        step_barrier();
    }

    __syncthreads();
    // ===== head: fc1(16)+relu, fc2(1) =====
    if (tid < NBB * 16){
        const int b = tid >> 4, j2 = tid & 15;
        float a = b_fc1[j2];
        #pragma unroll
        for (int kk = 0; kk < 32; ++kk) a = fmaf(W_fc1[j2*32 + kk], hfin[b][kk], a);
        hd[b][j2] = fmaxf(a, 0.f);
    }
    __syncthreads();
    if (tid < NBB){
        float a = b_fc2[0];
        #pragma unroll
        for (int kk = 0; kk < 16; ++kk) a = fmaf(W_fc2[kk], hd[tid][kk], a);
        out[b0 + tid] = a;
    }
}

extern "C" void kernel_launch(void* const* d_in, const int* in_sizes, int n_in,
                              void* d_out, int out_size, void* d_ws, size_t ws_size,
                              hipStream_t stream) {
    const float* x     = (const float*)d_in[0];
    const float* W_ih1 = (const float*)d_in[1];
    const float* W_hh1 = (const float*)d_in[2];
    const float* b_ih1 = (const float*)d_in[3];
    const float* b_hh1 = (const float*)d_in[4];
    const float* W_ih2 = (const float*)d_in[5];
    const float* W_hh2 = (const float*)d_in[6];
    const float* b_ih2 = (const float*)d_in[7];
    const float* b_hh2 = (const float*)d_in[8];
    const float* W_fc1 = (const float*)d_in[9];
    const float* b_fc1 = (const float*)d_in[10];
    const float* W_fc2 = (const float*)d_in[11];
    const float* b_fc2 = (const float*)d_in[12];
    float* out = (float*)d_out;

    const int B = in_sizes[0] / (T_ * F_);   // 4096
    dim3 grid(B / NBB), block(TPB);          // 256 blocks, 1/CU
    hipLaunchKernelGGL(lstm_mfma, grid, block, 0, stream,
                       x, W_ih1, W_hh1, b_ih1, b_hh1,
                       W_ih2, W_hh2, b_ih2, b_hh2,
                       W_fc1, b_fc1, W_fc2, b_fc2, out);
}

// Round 16
// 276.217 us; speedup vs baseline: 1.3609x; 1.1616x over previous
//
#include <hip/hip_runtime.h>

#define T_   256
#define F_   32
#define NBB  16     // full 16-wide fragments
#define TPB  768    // 12 waves: 0-7 L1-role (2 tiles), 8-11 L2-role (2 tiles)
#define IMW  104
#define PR1  260    // pre1 row stride (f32), 16B-aligned
#define PR2  132

typedef __attribute__((ext_vector_type(8))) short bf16x8;
typedef __attribute__((ext_vector_type(4))) float f32x4;

#define K1f  (-1.44269504f)   // -log2(e)   : sigmoid gates
#define K2f  (-2.88539008f)   // -2*log2(e) : tanh gate & tanh(c)

__device__ __forceinline__ unsigned short bf16_rne(float x){
    unsigned u = __float_as_uint(x);
    u += 0x7FFF + ((u >> 16) & 1);
    return (unsigned short)(u >> 16);
}
__device__ __forceinline__ void bf16_split(float x, unsigned short& h, unsigned short& l){
    h = bf16_rne(x);
    float xr = __uint_as_float(((unsigned)h) << 16);
    l = bf16_rne(x - xr);
}
__device__ __forceinline__ void make_frags_s(const float* __restrict__ p8, float s,
                                             bf16x8& fh, bf16x8& fl){
    #pragma unroll
    for (int e = 0; e < 8; ++e){
        unsigned short h, l; bf16_split(s * p8[e], h, l);
        fh[e] = (short)h; fl[e] = (short)l;
    }
}
__device__ __forceinline__ float sigm_pre(float p){   // p = -log2e*x
    return __builtin_amdgcn_rcpf(1.f + __builtin_amdgcn_exp2f(p));
}
__device__ __forceinline__ float tanh_pre(float p){   // p = -2log2e*x
    return fmaf(2.f, __builtin_amdgcn_rcpf(1.f + __builtin_amdgcn_exp2f(p)), -1.f);
}
__device__ __forceinline__ float unit_combine(float gi, float gf, float gg, float go, float& c){
    const float i_ = sigm_pre(gi);
    const float f_ = sigm_pre(gf);
    const float g_ = tanh_pre(gg);
    const float o_ = sigm_pre(go);
    c = fmaf(f_, c, i_ * g_);
    return o_ * tanh_pre(K2f * c);
}

#define MFMA(A,B,C) __builtin_amdgcn_mfma_f32_16x16x32_bf16((A),(B),(C),0,0,0)

// LDS-visibility barrier WITHOUT vmcnt drain (x-loads stay in flight).
__device__ __forceinline__ void step_barrier(){
    asm volatile("s_waitcnt lgkmcnt(0)" ::: "memory");
    __builtin_amdgcn_s_barrier();
}

// (768,3): 12 waves = 3/SIMD, VGPR cap ~168; per-wave need ~130 (2 tiles only).
__global__ __launch_bounds__(TPB, 3) void lstm_mfma(
    const float* __restrict__ x,      // [4096,256,32]
    const float* __restrict__ W_ih1,  // [256,32]
    const float* __restrict__ W_hh1,  // [256,64]
    const float* __restrict__ b_ih1,  // [256]
    const float* __restrict__ b_hh1,  // [256]
    const float* __restrict__ W_ih2,  // [128,64]
    const float* __restrict__ W_hh2,  // [128,32]
    const float* __restrict__ b_ih2,  // [128]
    const float* __restrict__ b_hh2,  // [128]
    const float* __restrict__ W_fc1,  // [16,32]
    const float* __restrict__ b_fc1,  // [16]
    const float* __restrict__ W_fc2,  // [1,16]
    const float* __restrict__ b_fc2,  // [1]
    float* __restrict__ out)          // [4096]
{
    const int tid  = threadIdx.x;
    const int lane = tid & 63;
    const int wid  = tid >> 6;        // 0..11
    const int bb   = lane & 15;       // fragment col = batch
    const int kg   = (lane >> 4) & 3; // k-group of 8
    const int b0   = blockIdx.x * NBB;

    __shared__ __align__(16) unsigned short i1h[2][NBB][IMW], i1l[2][NBB][IMW];
    __shared__ __align__(16) unsigned short i2h[2][NBB][IMW], i2l[2][NBB][IMW];
    __shared__ __align__(16) float pre1[NBB * PR1];
    __shared__ __align__(16) float pre2[NBB * PR2];
    __shared__ float hfin[NBB][32];
    __shared__ float hd[NBB][16];

    // ===== weight fragments: 2 tiles/wave =====
    // L1 (wid<8): tiles 2w,2w+1 of 16; tile T: gate T>>2, rowblock T&3
    // L2 (wid>=8): tiles 2j,2j+1 of 8; tile S: gate S>>1, rowblock S&1
    bf16x8 wh[2][3], wl[2][3];
    f32x4  bfr[2];
    int    offs[2];
    if (wid < 8){
        #pragma unroll
        for (int tt = 0; tt < 2; ++tt){
            const int Tt = 2*wid + tt;
            const int g = Tt >> 2, rb = Tt & 3;
            const float s = (g == 2) ? K2f : K1f;
            offs[tt] = 64*g + 16*rb;
            const int r = offs[tt] + bb;
            make_frags_s(&W_ih1[r*32 +      8*kg], s, wh[tt][0], wl[tt][0]);
            make_frags_s(&W_hh1[r*64 +      8*kg], s, wh[tt][1], wl[tt][1]);
            make_frags_s(&W_hh1[r*64 + 32 + 8*kg], s, wh[tt][2], wl[tt][2]);
            #pragma unroll
            for (int q = 0; q < 4; ++q){
                const int row = offs[tt] + 4*kg + q;
                bfr[tt][q] = s * (b_ih1[row] + b_hh1[row]);
            }
        }
    } else {
        const int j = wid - 8;
        #pragma unroll
        for (int tt = 0; tt < 2; ++tt){
            const int St = 2*j + tt;
            const int g = St >> 1, rb = St & 1;
            const float s = (g == 2) ? K2f : K1f;
            offs[tt] = 32*g + 16*rb;
            const int r = offs[tt] + bb;
            make_frags_s(&W_ih2[r*64 +      8*kg], s, wh[tt][0], wl[tt][0]);
            make_frags_s(&W_ih2[r*64 + 32 + 8*kg], s, wh[tt][1], wl[tt][1]);
            make_frags_s(&W_hh2[r*32 +      8*kg], s, wh[tt][2], wl[tt][2]);
            #pragma unroll
            for (int q = 0; q < 4; ++q){
                const int row = offs[tt] + 4*kg + q;
                bfr[tt][q] = s * (b_ih2[row] + b_hh2[row]);
            }
        }
    }

    // ===== combine ownership =====
    // L1-combine (tid<512, in P2): batch cb=tid>>5, units 2*(tid&31), +1
    const int cb = tid >> 5;
    const int u0 = (tid & 31) * 2;
    float c1a = 0.f, c1b = 0.f;
    // L2-combine + x (tid>=512, in P1): lt=tid-512, batch cb2=lt>>4, units 2*(lt&15), +1
    const int lt  = tid & 255;
    const int cb2 = lt >> 4;
    const int v0  = (lt & 15) * 2;
    float c2a = 0.f, c2b = 0.f;
    const int xf = (lt & 15) * 2;
    const size_t xbase = (size_t)(b0 + cb2) * (T_*F_) + xf;
    float2 xc = make_float2(0.f, 0.f);

    // ===== init: zero images, stage x(0), preload x(1) =====
    for (int i = tid; i < 2*NBB*IMW; i += TPB){
        (&i1h[0][0][0])[i] = 0; (&i1l[0][0][0])[i] = 0;
        (&i2h[0][0][0])[i] = 0; (&i2l[0][0][0])[i] = 0;
    }
    __syncthreads();
    if (wid >= 8){
        float2 x0 = *(const float2*)&x[xbase];
        unsigned short hh, hl;
        bf16_split(x0.x, hh, hl); i1h[0][cb2][xf]   = hh; i1l[0][cb2][xf]   = hl;
        bf16_split(x0.y, hh, hl); i1h[0][cb2][xf+1] = hh; i1l[0][cb2][xf+1] = hl;
        xc = *(const float2*)&x[xbase + F_];
    }
    __syncthreads();

    // ===== main loop (r13 schedule, redistributed) =====
    // P1(t): L1-MFMA(t)->pre1 [w0-7]  |  L2-combine(t-2)->i2[nxt] + x(t+1)->i1[nxt] [w8-11]
    // P2(t): L1-combine(t)->i1[nxt],i2[cur] [w0-7]  |  L2-MFMA(t-1) from i2[nxt]->pre2 [w8-11]
    for (int t = 0; t <= T_ + 1; ++t){
        const int cur = t & 1, nxt = cur ^ 1;

        // ---------- P1 ----------
        if (wid < 8){
            if (t < T_){
                const unsigned short* ph = &i1h[cur][0][0] + bb*IMW + 8*kg;
                const unsigned short* pl = &i1l[cur][0][0] + bb*IMW + 8*kg;
                bf16x8 vh[3], vl[3];
                #pragma unroll
                for (int kb = 0; kb < 3; ++kb){
                    vh[kb] = *(const bf16x8*)(ph + 32*kb);
                    vl[kb] = *(const bf16x8*)(pl + 32*kb);
                }
                __builtin_amdgcn_s_setprio(1);
                f32x4 a0 = bfr[0], a1 = bfr[1];
                #pragma unroll
                for (int kb = 0; kb < 3; ++kb){
                    a0 = MFMA(wh[0][kb], vh[kb], a0);
                    a1 = MFMA(wh[1][kb], vh[kb], a1);
                }
                #pragma unroll
                for (int kb = 0; kb < 3; ++kb){
                    a0 = MFMA(wl[0][kb], vh[kb], a0);
                    a1 = MFMA(wl[1][kb], vh[kb], a1);
                }
                #pragma unroll
                for (int kb = 0; kb < 3; ++kb){
                    a0 = MFMA(wh[0][kb], vl[kb], a0);
                    a1 = MFMA(wh[1][kb], vl[kb], a1);
                }
                __builtin_amdgcn_s_setprio(0);
                *(f32x4*)&pre1[bb*PR1 + offs[0] + 4*kg] = a0;
                *(f32x4*)&pre1[bb*PR1 + offs[1] + 4*kg] = a1;
            }
        } else {
            const int m = t - 2;
            if (m >= 0 && m < T_){
                const float* p = &pre2[cb2*PR2];
                const float2 gi = *(const float2*)&p[     v0];
                const float2 gf = *(const float2*)&p[32 + v0];
                const float2 gg = *(const float2*)&p[64 + v0];
                const float2 go = *(const float2*)&p[96 + v0];
                const float h0 = unit_combine(gi.x, gf.x, gg.x, go.x, c2a);
                const float h1 = unit_combine(gi.y, gf.y, gg.y, go.y, c2b);
                unsigned short h0h, h0l, h1h, h1l;
                bf16_split(h0, h0h, h0l); bf16_split(h1, h1h, h1l);
                *(unsigned*)&i2h[nxt][cb2][64 + v0] = (unsigned)h0h | ((unsigned)h1h << 16);
                *(unsigned*)&i2l[nxt][cb2][64 + v0] = (unsigned)h0l | ((unsigned)h1l << 16);
                if (m == T_ - 1){ hfin[cb2][v0] = h0; hfin[cb2][v0+1] = h1; }
            }
            if (t + 1 < T_){
                unsigned short hh, hl;
                bf16_split(xc.x, hh, hl);
                const unsigned w0h = hh, w0l = hl;
                bf16_split(xc.y, hh, hl);
                *(unsigned*)&i1h[nxt][cb2][xf] = w0h | ((unsigned)hh << 16);
                *(unsigned*)&i1l[nxt][cb2][xf] = w0l | ((unsigned)hl << 16);
                const int tn = (t + 2 < T_) ? t + 2 : T_ - 1;
                xc = *(const float2*)&x[xbase + (size_t)tn * F_];
            }
        }
        step_barrier();

        // ---------- P2 ----------
        if (wid < 8){
            if (t < T_){
                const float* p = &pre1[cb*PR1];
                const float2 gi = *(const float2*)&p[      u0];
                const float2 gf = *(const float2*)&p[ 64 + u0];
                const float2 gg = *(const float2*)&p[128 + u0];
                const float2 go = *(const float2*)&p[192 + u0];
                const float h0 = unit_combine(gi.x, gf.x, gg.x, go.x, c1a);
                const float h1 = unit_combine(gi.y, gf.y, gg.y, go.y, c1b);
                unsigned short h0h, h0l, h1h, h1l;
                bf16_split(h0, h0h, h0l); bf16_split(h1, h1h, h1l);
                const unsigned wh_ = (unsigned)h0h | ((unsigned)h1h << 16);
                const unsigned wl_ = (unsigned)h0l | ((unsigned)h1l << 16);
                *(unsigned*)&i1h[nxt][cb][32 + u0] = wh_;   // h1(t) for L1-MFMA(t+1)
                *(unsigned*)&i1l[nxt][cb][32 + u0] = wl_;
                *(unsigned*)&i2h[cur][cb][u0]      = wh_;   // h1(t) for L2-MFMA(t)
                *(unsigned*)&i2l[cur][cb][u0]      = wl_;
            }
        } else {
            const int k = t - 1;
            if (k >= 0 && k < T_){
                // i2[nxt] = [h1(k) | h2(k-1)]
                const unsigned short* ph = &i2h[nxt][0][0] + bb*IMW + 8*kg;
                const unsigned short* pl = &i2l[nxt][0][0] + bb*IMW + 8*kg;
                bf16x8 vh[3], vl[3];
                #pragma unroll
                for (int kb = 0; kb < 3; ++kb){
                    vh[kb] = *(const bf16x8*)(ph + 32*kb);
                    vl[kb] = *(const bf16x8*)(pl + 32*kb);
                }
                __builtin_amdgcn_s_setprio(1);
                f32x4 a0 = bfr[0], a1 = bfr[1];
                #pragma unroll
                for (int kb = 0; kb < 3; ++kb){
                    a0 = MFMA(wh[0][kb], vh[kb], a0);
                    a1 = MFMA(wh[1][kb], vh[kb], a1);
                }
                #pragma unroll
                for (int kb = 0; kb < 3; ++kb){
                    a0 = MFMA(wl[0][kb], vh[kb], a0);
                    a1 = MFMA(wl[1][kb], vh[kb], a1);
                }
                #pragma unroll
                for (int kb = 0; kb < 3; ++kb){
                    a0 = MFMA(wh[0][kb], vl[kb], a0);
                    a1 = MFMA(wh[1][kb], vl[kb], a1);
                }
                __builtin_amdgcn_s_setprio(0);
                *(f32x4*)&pre2[bb*PR2 + offs[0] + 4*kg] = a0;
                *(f32x4*)&pre2[bb*PR2 + offs[1] + 4*kg] = a1;
            }
        }
        step_barrier();
    }

    __syncthreads();
    // ===== head: fc1(16)+relu, fc2(1) =====
    if (tid < NBB * 16){
        const int b = tid >> 4, j2 = tid & 15;
        float a = b_fc1[j2];
        #pragma unroll
        for (int kk = 0; kk < 32; ++kk) a = fmaf(W_fc1[j2*32 + kk], hfin[b][kk], a);
        hd[b][j2] = fmaxf(a, 0.f);
    }
    __syncthreads();
    if (tid < NBB){
        float a = b_fc2[0];
        #pragma unroll
        for (int kk = 0; kk < 16; ++kk) a = fmaf(W_fc2[kk], hd[tid][kk], a);
        out[b0 + tid] = a;
    }
}

extern "C" void kernel_launch(void* const* d_in, const int* in_sizes, int n_in,
                              void* d_out, int out_size, void* d_ws, size_t ws_size,
                              hipStream_t stream) {
    const float* x     = (const float*)d_in[0];
    const float* W_ih1 = (const float*)d_in[1];
    const float* W_hh1 = (const float*)d_in[2];
    const float* b_ih1 = (const float*)d_in[3];
    const float* b_hh1 = (const float*)d_in[4];
    const float* W_ih2 = (const float*)d_in[5];
    const float* W_hh2 = (const float*)d_in[6];
    const float* b_ih2 = (const float*)d_in[7];
    const float* b_hh2 = (const float*)d_in[8];
    const float* W_fc1 = (const float*)d_in[9];
    const float* b_fc1 = (const float*)d_in[10];
    const float* W_fc2 = (const float*)d_in[11];
    const float* b_fc2 = (const float*)d_in[12];
    float* out = (float*)d_out;

    const int B = in_sizes[0] / (T_ * F_);   // 4096
    dim3 grid(B / NBB), block(TPB);          // 256 blocks, 1/CU, 12 waves
    hipLaunchKernelGGL(lstm_mfma, grid, block, 0, stream,
                       x, W_ih1, W_hh1, b_ih1, b_hh1,
                       W_ih2, W_hh2, b_ih2, b_hh2,
                       W_fc1, b_fc1, W_fc2, b_fc2, out);
}